// Round 8
// baseline (11376.483 us; speedup 1.0000x reference)
//
#include <hip/hip_runtime.h>
#include <math.h>

#define S_ 48
#define B_ 64
#define D_ 300
#define HE_ 300
#define HD_ 256
#define E_ 50
#define A_ 128
#define T_ 50
#define N_ (S_*B_)   // 3072

__device__ __forceinline__ float sigm(float x){ return 1.0f/(1.0f + expf(-x)); }

// ---------------------------------------------------------------------------
// Generic GEMM: C(M,N) = A(M,K) @ W(N,K)^T + bias(N)
// MODE 0: store C row-major (A2 unused)
// MODE 2: A-tile = A + A2 elementwise; v = tanh(acc+bias);
//         cols [0,256) -> C[m*256+n], [256,512) -> C2
// ---------------------------------------------------------------------------
template<int MODE>
__global__ __launch_bounds__(256)
void gemm_bias_kernel(const float* __restrict__ A, const float* __restrict__ A2,
                      const float* __restrict__ W,
                      const float* __restrict__ bias, float* __restrict__ C,
                      float* __restrict__ C2, int M, int N, int K)
{
  __shared__ float As[16][64];
  __shared__ float Ws[16][64];
  const int tid = threadIdx.x;
  const int bm = blockIdx.y * 64;
  const int bn = blockIdx.x * 64;
  const int tx = tid & 15, ty = tid >> 4;
  const int lr = tid >> 2;
  const int lk = (tid & 3) << 2;
  float acc[4][4] = {{0.f}};
  for (int kb = 0; kb < K; kb += 16) {
    {
      const int row = bm + lr;
      const int k = kb + lk;
      const float* ap = A + (size_t)row * K + k;
      float4 v = make_float4(0.f,0.f,0.f,0.f);
      if (k + 3 < K) v = *reinterpret_cast<const float4*>(ap);
      else {
        if (k   < K) v.x = ap[0];
        if (k+1 < K) v.y = ap[1];
        if (k+2 < K) v.z = ap[2];
        if (k+3 < K) v.w = ap[3];
      }
      if (MODE == 2) {
        const float* ap2 = A2 + (size_t)row * K + k;
        if (k + 3 < K) {
          float4 v2 = *reinterpret_cast<const float4*>(ap2);
          v.x += v2.x; v.y += v2.y; v.z += v2.z; v.w += v2.w;
        } else {
          if (k   < K) v.x += ap2[0];
          if (k+1 < K) v.y += ap2[1];
          if (k+2 < K) v.z += ap2[2];
          if (k+3 < K) v.w += ap2[3];
        }
      }
      As[lk][lr]=v.x; As[lk+1][lr]=v.y; As[lk+2][lr]=v.z; As[lk+3][lr]=v.w;
    }
    {
      const int col = bn + lr;
      const int k = kb + lk;
      float4 v = make_float4(0.f,0.f,0.f,0.f);
      if (col < N) {
        const float* wp = W + (size_t)col * K + k;
        if (k + 3 < K) v = *reinterpret_cast<const float4*>(wp);
        else {
          if (k   < K) v.x = wp[0];
          if (k+1 < K) v.y = wp[1];
          if (k+2 < K) v.z = wp[2];
          if (k+3 < K) v.w = wp[3];
        }
      }
      Ws[lk][lr]=v.x; Ws[lk+1][lr]=v.y; Ws[lk+2][lr]=v.z; Ws[lk+3][lr]=v.w;
    }
    __syncthreads();
    #pragma unroll
    for (int kk = 0; kk < 16; ++kk) {
      float4 a4 = *reinterpret_cast<const float4*>(&As[kk][ty<<2]);
      float4 w4 = *reinterpret_cast<const float4*>(&Ws[kk][tx<<2]);
      const float* a = reinterpret_cast<const float*>(&a4);
      const float* w = reinterpret_cast<const float*>(&w4);
      #pragma unroll
      for (int i = 0; i < 4; ++i)
        #pragma unroll
        for (int j = 0; j < 4; ++j)
          acc[i][j] = fmaf(a[i], w[j], acc[i][j]);
    }
    __syncthreads();
  }
  #pragma unroll
  for (int i = 0; i < 4; ++i) {
    const int m = bm + (ty<<2) + i;
    #pragma unroll
    for (int j = 0; j < 4; ++j) {
      const int n = bn + (tx<<2) + j;
      if (n < N) {
        float v = acc[i][j] + bias[n];
        if (MODE == 0) {
          C[(size_t)m*N + n] = v;
        } else {
          v = tanhf(v);
          if (n < HD_) C[(size_t)m*HD_ + n] = v;
          else         C2[(size_t)m*HD_ + (n-HD_)] = v;
        }
      }
    }
  }
}

// ---------------------------------------------------------------------------
// Padded transpose into strided destination:
// out[(row0+k)*dstride + coff + gc] = in[gc*NK + k]  (zero for k in [NK,NKP))
// ---------------------------------------------------------------------------
__global__ __launch_bounds__(256)
void ctranspose_kernel(const float* __restrict__ in, float* __restrict__ out,
                       int NC, int NK, int NKP, int dstride, int row0, int coff)
{
  int idx = blockIdx.x * 256 + threadIdx.x;
  if (idx < NC*NKP) {
    int gc = idx / NKP, k = idx % NKP;
    out[(size_t)(row0+k)*dstride + coff + gc] =
        (k < NK) ? in[(size_t)gc*NK + k] : 0.0f;
  }
}

// ---------------------------------------------------------------------------
// Pack decoder cell-0 stream: 39 tiles x 6144 floats.
// Tile t<13 (kq=t): rows 0-3 = WhhT0 k=4t+row (operand h0s);
//                   rows 4-7 = WihT0 k=4t+(row-4) (operand es; k>=50 zero).
// Tile t>=13: 8 rows = WhhT0 k = 52+8(t-13)+row (zero past k=255).
// Reproduces round-6 FMA order exactly (hh quad then ih quad per kq<13).
// ---------------------------------------------------------------------------
__global__ __launch_bounds__(256)
void pack_dec0_kernel(const float* __restrict__ Whh, const float* __restrict__ Wih,
                      float* __restrict__ out)
{
  int idx = blockIdx.x * 256 + threadIdx.x;
  if (idx >= 39*6144) return;
  int t  = idx / 6144;
  int w  = idx % 6144;
  int rr = w / 768;
  int gc = w % 768;
  float v = 0.0f;
  if (t < 13) {
    int k = t*4 + (rr & 3);
    if (rr < 4) v = Whh[(size_t)gc*HD_ + k];
    else if (k < E_) v = Wih[(size_t)gc*E_ + k];
  } else {
    int k = 52 + (t-13)*8 + rr;
    if (k < HD_) v = Whh[(size_t)gc*HD_ + k];
  }
  out[idx] = v;
}

// ---------------------------------------------------------------------------
// Persistent encoder layer: grid (16 row-groups, 2 dirs) = 32 blocks, 640 thr.
// (round-6 proven, verbatim)
// ---------------------------------------------------------------------------
template<int LAYER>
__global__ __launch_bounds__(640, 2)
void enc_layer_persistent(const float* __restrict__ gi_f, const float* __restrict__ gi_b,
                          const float* __restrict__ WhhT_f, const float* __restrict__ WhhT_b,
                          const float* __restrict__ bhh_f, const float* __restrict__ bhh_b,
                          float* __restrict__ out, float* __restrict__ outB)
{
  const int dir = blockIdx.y;
  const float* gi  = dir ? gi_b   : gi_f;
  const float* WT  = dir ? WhhT_b : WhhT_f;
  const float* bhh = dir ? bhh_b  : bhh_f;
  float* o = (LAYER == 1 && dir) ? outB : out;

  __shared__ float hA[4][304];
  __shared__ float hB[4][304];
  const int tid = threadIdx.x;
  const int half = tid / 320;
  const int j = tid - half*320;
  const int R0 = blockIdx.x * 4;
  const int r0 = half * 2;
  const bool act = (j < HE_);

  float b_r = 0.f, b_z = 0.f, b_n = 0.f;
  if (act) { b_r = bhh[j]; b_z = bhh[HE_+j]; b_n = bhh[2*HE_+j]; }
  __syncthreads();

  for (int t = 0; t < S_; ++t) {
    const int tt = dir ? (S_-1 - t) : t;
    float (*hin)[304]  = (t & 1) ? hB : hA;
    float (*hout)[304] = (t & 1) ? hA : hB;
    float ar[2]={0,0}, az[2]={0,0}, an[2]={0,0};
    if (act && t > 0) {
      for (int k = 0; k < HE_; k += 4) {
        float wr[4], wz[4], wn[4];
        #pragma unroll
        for (int u = 0; u < 4; ++u) {
          const float* wk = WT + (size_t)(k+u)*(3*HE_);
          wr[u] = wk[j]; wz[u] = wk[HE_+j]; wn[u] = wk[2*HE_+j];
        }
        #pragma unroll
        for (int r = 0; r < 2; ++r) {
          float4 h4 = *reinterpret_cast<const float4*>(&hin[r0+r][k]);
          ar[r]=fmaf(h4.x,wr[0],ar[r]); ar[r]=fmaf(h4.y,wr[1],ar[r]);
          ar[r]=fmaf(h4.z,wr[2],ar[r]); ar[r]=fmaf(h4.w,wr[3],ar[r]);
          az[r]=fmaf(h4.x,wz[0],az[r]); az[r]=fmaf(h4.y,wz[1],az[r]);
          az[r]=fmaf(h4.z,wz[2],az[r]); az[r]=fmaf(h4.w,wz[3],az[r]);
          an[r]=fmaf(h4.x,wn[0],an[r]); an[r]=fmaf(h4.y,wn[1],an[r]);
          an[r]=fmaf(h4.z,wn[2],an[r]); an[r]=fmaf(h4.w,wn[3],an[r]);
        }
      }
    }
    if (act) {
      #pragma unroll
      for (int r = 0; r < 2; ++r) {
        const int row = R0 + r0 + r;
        const size_t gb = (size_t)(tt*B_ + row) * (3*HE_);
        float gr = gi[gb + j];
        float gz = gi[gb + HE_ + j];
        float gn = gi[gb + 2*HE_ + j];
        float rg = sigm(gr + ar[r] + b_r);
        float zg = sigm(gz + az[r] + b_z);
        float ng = tanhf(gn + rg*(an[r] + b_n));
        float ho = (t > 0) ? hin[r0+r][j] : 0.0f;
        float hn = (1.0f - zg)*ng + zg*ho;
        hout[r0+r][j] = hn;
        if (LAYER == 0) o[(size_t)(tt*B_ + row)*(2*HE_) + dir*HE_ + j] = hn;
        else            o[(size_t)(tt*B_ + row)*HE_ + j] = hn;
      }
    }
    __syncthreads();
  }
}

// ---------------------------------------------------------------------------
// Persistent decoder with LDS weight staging. 256 blocks x 512 threads.
// Weights global->reg->LDS double-buffered; all 8 waves read from LDS.
// Cell0: 39-tile Wc0 stream (pack_dec0 layout) -- FMA order == round 6.
// Cell1: 32 tiles of 8k x 1536 over Wc1T ([0,768)=WihT1, [768,1536)=WhhT1).
// ---------------------------------------------------------------------------
__global__ __launch_bounds__(512)
void dec_persistent(const float* __restrict__ Wc0,
                    const float* __restrict__ Wc1T,
                    const float* __restrict__ WoutT,  // [256][128]
                    const float* __restrict__ bih0, const float* __restrict__ bhh0,
                    const float* __restrict__ bih1, const float* __restrict__ bhh1,
                    const float* __restrict__ bout,
                    const float* __restrict__ emb,
                    const float* __restrict__ h0init, const float* __restrict__ h1init,
                    float* __restrict__ Y)
{
  __shared__ __align__(16) float wb[2][12288];   // 96 KB staging (dbuf)
  __shared__ __align__(16) float h0s[12][256];
  __shared__ __align__(16) float h1s[12][256];
  __shared__ __align__(16) float es[12][56];
  const int tid = threadIdx.x;
  const int R0 = blockIdx.x * 12;
  const int c  = tid & 255;
  const int half = tid >> 8;
  const int r0 = half * 6;
  const int lane = tid & 63;
  const int wave = tid >> 6;

  for (int i = tid; i < 12*64; i += 512) {
    int r = i >> 6, k = (i & 63) << 2;
    *reinterpret_cast<float4*>(&h0s[r][k]) =
        *reinterpret_cast<const float4*>(&h0init[(size_t)(R0+r)*HD_ + k]);
    *reinterpret_cast<float4*>(&h1s[r][k]) =
        *reinterpret_cast<const float4*>(&h1init[(size_t)(R0+r)*HD_ + k]);
  }
  for (int i = tid; i < 12*56; i += 512) {
    int r = i / 56, k = i - r*56;
    es[r][k] = (k < E_) ? emb[E_ + k] : 0.0f;   // emb[SOS=1], zero pad
  }
  const float b0r = bih0[c] + bhh0[c];
  const float b0z = bih0[HD_+c] + bhh0[HD_+c];
  const float b0ni = bih0[2*HD_+c];
  const float b0nh = bhh0[2*HD_+c];
  const float b1r = bih1[c] + bhh1[c];
  const float b1z = bih1[HD_+c] + bhh1[HD_+c];
  const float b1ni = bih1[2*HD_+c];
  const float b1nh = bhh1[2*HD_+c];
  const float bo0 = bout[lane];
  const float bo1 = bout[64 + lane];
  __syncthreads();

  for (int s = 0; s < T_-1; ++s) {
    float ar[6]={0,0,0,0,0,0}, az[6]={0,0,0,0,0,0};
    float ani[6]={0,0,0,0,0,0}, anh[6]={0,0,0,0,0,0};
    // ================= cell 0: 39 tiles of 6144 over Wc0 ==================
    #pragma unroll
    for (int j = 0; j < 3; ++j) {
      *reinterpret_cast<float4*>(&wb[0][(tid + j*512)*4]) =
          *reinterpret_cast<const float4*>(Wc0 + (size_t)(tid + j*512)*4);
    }
    __syncthreads();
    int cur = 0;
    for (int t = 0; t < 39; ++t) {
      float4 nv0, nv1, nv2;
      if (t < 38) {
        const float* src = Wc0 + (size_t)(t+1)*6144;
        nv0 = *reinterpret_cast<const float4*>(src + (size_t)tid*4);
        nv1 = *reinterpret_cast<const float4*>(src + (size_t)(tid+512)*4);
        nv2 = *reinterpret_cast<const float4*>(src + (size_t)(tid+1024)*4);
      }
      const float* w = wb[cur];
      if (t < 13) {
        const int k0 = t*4;     // kq = t: hh quad then ih quad (round-6 order)
        {
          float wr[4], wz[4], wn[4];
          #pragma unroll
          for (int u = 0; u < 4; ++u) {
            wr[u] = w[u*768 + c];
            wz[u] = w[u*768 + 256 + c];
            wn[u] = w[u*768 + 512 + c];
          }
          #pragma unroll
          for (int r = 0; r < 6; ++r) {
            float4 x = *reinterpret_cast<const float4*>(&h0s[r0+r][k0]);
            ar[r]=fmaf(x.x,wr[0],ar[r]); ar[r]=fmaf(x.y,wr[1],ar[r]);
            ar[r]=fmaf(x.z,wr[2],ar[r]); ar[r]=fmaf(x.w,wr[3],ar[r]);
            az[r]=fmaf(x.x,wz[0],az[r]); az[r]=fmaf(x.y,wz[1],az[r]);
            az[r]=fmaf(x.z,wz[2],az[r]); az[r]=fmaf(x.w,wz[3],az[r]);
            anh[r]=fmaf(x.x,wn[0],anh[r]); anh[r]=fmaf(x.y,wn[1],anh[r]);
            anh[r]=fmaf(x.z,wn[2],anh[r]); anh[r]=fmaf(x.w,wn[3],anh[r]);
          }
        }
        {
          float vr[4], vz[4], vn[4];
          #pragma unroll
          for (int u = 0; u < 4; ++u) {
            vr[u] = w[(4+u)*768 + c];
            vz[u] = w[(4+u)*768 + 256 + c];
            vn[u] = w[(4+u)*768 + 512 + c];
          }
          #pragma unroll
          for (int r = 0; r < 6; ++r) {
            float4 e = *reinterpret_cast<const float4*>(&es[r0+r][k0]);
            ar[r]=fmaf(e.x,vr[0],ar[r]); ar[r]=fmaf(e.y,vr[1],ar[r]);
            ar[r]=fmaf(e.z,vr[2],ar[r]); ar[r]=fmaf(e.w,vr[3],ar[r]);
            az[r]=fmaf(e.x,vz[0],az[r]); az[r]=fmaf(e.y,vz[1],az[r]);
            az[r]=fmaf(e.z,vz[2],az[r]); az[r]=fmaf(e.w,vz[3],az[r]);
            ani[r]=fmaf(e.x,vn[0],ani[r]); ani[r]=fmaf(e.y,vn[1],ani[r]);
            ani[r]=fmaf(e.z,vn[2],ani[r]); ani[r]=fmaf(e.w,vn[3],ani[r]);
          }
        }
      } else {
        const int k0 = 52 + (t-13)*8;   // kq pair, ascending k
        #pragma unroll
        for (int hh = 0; hh < 2; ++hh) {
          const int k = k0 + hh*4;
          if (k < HD_) {
            float wr[4], wz[4], wn[4];
            #pragma unroll
            for (int u = 0; u < 4; ++u) {
              wr[u] = w[(hh*4+u)*768 + c];
              wz[u] = w[(hh*4+u)*768 + 256 + c];
              wn[u] = w[(hh*4+u)*768 + 512 + c];
            }
            #pragma unroll
            for (int r = 0; r < 6; ++r) {
              float4 x = *reinterpret_cast<const float4*>(&h0s[r0+r][k]);
              ar[r]=fmaf(x.x,wr[0],ar[r]); ar[r]=fmaf(x.y,wr[1],ar[r]);
              ar[r]=fmaf(x.z,wr[2],ar[r]); ar[r]=fmaf(x.w,wr[3],ar[r]);
              az[r]=fmaf(x.x,wz[0],az[r]); az[r]=fmaf(x.y,wz[1],az[r]);
              az[r]=fmaf(x.z,wz[2],az[r]); az[r]=fmaf(x.w,wz[3],az[r]);
              anh[r]=fmaf(x.x,wn[0],anh[r]); anh[r]=fmaf(x.y,wn[1],anh[r]);
              anh[r]=fmaf(x.z,wn[2],anh[r]); anh[r]=fmaf(x.w,wn[3],anh[r]);
            }
          }
        }
      }
      if (t < 38) {
        float* dst = wb[cur^1];
        *reinterpret_cast<float4*>(&dst[(size_t)tid*4])        = nv0;
        *reinterpret_cast<float4*>(&dst[(size_t)(tid+512)*4])  = nv1;
        *reinterpret_cast<float4*>(&dst[(size_t)(tid+1024)*4]) = nv2;
      }
      __syncthreads();
      cur ^= 1;
    }
    {
      float hnew[6];
      #pragma unroll
      for (int r = 0; r < 6; ++r) {
        float rg = sigm(ar[r] + b0r);
        float zg = sigm(az[r] + b0z);
        float ng = tanhf(ani[r] + b0ni + rg*(anh[r] + b0nh));
        float hold = h0s[r0+r][c];
        hnew[r] = (1.0f - zg)*ng + zg*hold;
      }
      #pragma unroll
      for (int r = 0; r < 6; ++r) h0s[r0+r][c] = hnew[r];
    }
    __syncthreads();
    // ================= cell 1: 32 tiles of 8k x 1536 over Wc1T ============
    #pragma unroll
    for (int r = 0; r < 6; ++r) { ar[r]=0.f; az[r]=0.f; ani[r]=0.f; anh[r]=0.f; }
    #pragma unroll
    for (int j = 0; j < 6; ++j) {
      *reinterpret_cast<float4*>(&wb[0][(tid + j*512)*4]) =
          *reinterpret_cast<const float4*>(Wc1T + (size_t)(tid + j*512)*4);
    }
    __syncthreads();
    cur = 0;
    for (int t = 0; t < 32; ++t) {
      float4 nv[6];
      if (t < 31) {
        const float* src = Wc1T + (size_t)(t+1)*12288;
        #pragma unroll
        for (int j = 0; j < 6; ++j)
          nv[j] = *reinterpret_cast<const float4*>(src + (size_t)(tid + j*512)*4);
      }
      const float* w = wb[cur];
      const int k0 = t*8;
      #pragma unroll
      for (int kk = 0; kk < 8; kk += 4) {
        float vr[4], vz[4], vn[4], wr[4], wz[4], wn[4];
        #pragma unroll
        for (int u = 0; u < 4; ++u) {
          const int base = (kk+u)*1536;
          vr[u] = w[base + c];        vz[u] = w[base + 256 + c];
          vn[u] = w[base + 512 + c];  wr[u] = w[base + 768 + c];
          wz[u] = w[base + 1024 + c]; wn[u] = w[base + 1280 + c];
        }
        #pragma unroll
        for (int r = 0; r < 6; ++r) {
          float4 x = *reinterpret_cast<const float4*>(&h0s[r0+r][k0+kk]);
          ar[r]=fmaf(x.x,vr[0],ar[r]); ar[r]=fmaf(x.y,vr[1],ar[r]);
          ar[r]=fmaf(x.z,vr[2],ar[r]); ar[r]=fmaf(x.w,vr[3],ar[r]);
          az[r]=fmaf(x.x,vz[0],az[r]); az[r]=fmaf(x.y,vz[1],az[r]);
          az[r]=fmaf(x.z,vz[2],az[r]); az[r]=fmaf(x.w,vz[3],az[r]);
          ani[r]=fmaf(x.x,vn[0],ani[r]); ani[r]=fmaf(x.y,vn[1],ani[r]);
          ani[r]=fmaf(x.z,vn[2],ani[r]); ani[r]=fmaf(x.w,vn[3],ani[r]);
          float4 y = *reinterpret_cast<const float4*>(&h1s[r0+r][k0+kk]);
          ar[r]=fmaf(y.x,wr[0],ar[r]); ar[r]=fmaf(y.y,wr[1],ar[r]);
          ar[r]=fmaf(y.z,wr[2],ar[r]); ar[r]=fmaf(y.w,wr[3],ar[r]);
          az[r]=fmaf(y.x,wz[0],az[r]); az[r]=fmaf(y.y,wz[1],az[r]);
          az[r]=fmaf(y.z,wz[2],az[r]); az[r]=fmaf(y.w,wz[3],az[r]);
          anh[r]=fmaf(y.x,wn[0],anh[r]); anh[r]=fmaf(y.y,wn[1],anh[r]);
          anh[r]=fmaf(y.z,wn[2],anh[r]); anh[r]=fmaf(y.w,wn[3],anh[r]);
        }
      }
      if (t < 31) {
        float* dst = wb[cur^1];
        #pragma unroll
        for (int j = 0; j < 6; ++j)
          *reinterpret_cast<float4*>(&dst[(size_t)(tid + j*512)*4]) = nv[j];
      }
      __syncthreads();
      cur ^= 1;
    }
    {
      float hnew[6];
      #pragma unroll
      for (int r = 0; r < 6; ++r) {
        float rg = sigm(ar[r] + b1r);
        float zg = sigm(az[r] + b1z);
        float ng = tanhf(ani[r] + b1ni + rg*(anh[r] + b1nh));
        float hold = h1s[r0+r][c];
        hnew[r] = (1.0f - zg)*ng + zg*hold;
      }
      #pragma unroll
      for (int r = 0; r < 6; ++r) h1s[r0+r][c] = hnew[r];
    }
    __syncthreads();
    // ===== logits + log_softmax + argmax + emb feedback (8 waves, rr+=8) ===
    for (int rr = wave; rr < 12; rr += 8) {
      float a0 = 0.f, a1 = 0.f;
      for (int k = 0; k < HD_; k += 2) {
        float w00 = WoutT[(size_t)k*A_ + lane];
        float w01 = WoutT[(size_t)k*A_ + 64 + lane];
        float w10 = WoutT[(size_t)(k+1)*A_ + lane];
        float w11 = WoutT[(size_t)(k+1)*A_ + 64 + lane];
        float2 hv = *reinterpret_cast<const float2*>(&h1s[rr][k]);
        a0 = fmaf(hv.x, w00, a0); a0 = fmaf(hv.y, w10, a0);
        a1 = fmaf(hv.x, w01, a1); a1 = fmaf(hv.y, w11, a1);
      }
      float v0 = a0 + bo0;
      float v1 = a1 + bo1;
      float mx = fmaxf(v0, v1);
      #pragma unroll
      for (int off = 32; off >= 1; off >>= 1) mx = fmaxf(mx, __shfl_xor(mx, off));
      float sum = expf(v0 - mx) + expf(v1 - mx);
      #pragma unroll
      for (int off = 32; off >= 1; off >>= 1) sum += __shfl_xor(sum, off);
      float lz = mx + logf(sum);
      float* Yr = Y + ((size_t)s*N_ + R0 + rr)*A_;
      Yr[lane]      = v0 - lz;
      Yr[64 + lane] = v1 - lz;
      float bv; int bi;
      if (v0 >= v1) { bv = v0; bi = lane; } else { bv = v1; bi = 64 + lane; }
      #pragma unroll
      for (int off = 32; off >= 1; off >>= 1) {
        float ov = __shfl_xor(bv, off);
        int   oi = __shfl_xor(bi, off);
        if (ov > bv || (ov == bv && oi < bi)) { bv = ov; bi = oi; }
      }
      if (lane < E_) es[rr][lane] = emb[(size_t)bi*E_ + lane];
    }
    __syncthreads();
  }
}

// ---------------------------------------------------------------------------
extern "C" void kernel_launch(void* const* d_in, const int* in_sizes, int n_in,
                              void* d_out, int out_size, void* d_ws, size_t ws_size,
                              hipStream_t stream)
{
  (void)in_sizes; (void)n_in; (void)out_size; (void)ws_size;
  const float* wv      = (const float*)d_in[0];
  const float* e0f_Wih = (const float*)d_in[1];
  const float* e0f_Whh = (const float*)d_in[2];
  const float* e0f_bih = (const float*)d_in[3];
  const float* e0f_bhh = (const float*)d_in[4];
  const float* e0b_Wih = (const float*)d_in[5];
  const float* e0b_Whh = (const float*)d_in[6];
  const float* e0b_bih = (const float*)d_in[7];
  const float* e0b_bhh = (const float*)d_in[8];
  const float* e1f_Wih = (const float*)d_in[9];
  const float* e1f_Whh = (const float*)d_in[10];
  const float* e1f_bih = (const float*)d_in[11];
  const float* e1f_bhh = (const float*)d_in[12];
  const float* e1b_Wih = (const float*)d_in[13];
  const float* e1b_Whh = (const float*)d_in[14];
  const float* e1b_bih = (const float*)d_in[15];
  const float* e1b_bhh = (const float*)d_in[16];
  const float* d0_Wih  = (const float*)d_in[17];
  const float* d0_Whh  = (const float*)d_in[18];
  const float* d0_bih  = (const float*)d_in[19];
  const float* d0_bhh  = (const float*)d_in[20];
  const float* d1_Wih  = (const float*)d_in[21];
  const float* d1_Whh  = (const float*)d_in[22];
  const float* d1_bih  = (const float*)d_in[23];
  const float* d1_bhh  = (const float*)d_in[24];
  const float* emb     = (const float*)d_in[25];
  const float* Wout    = (const float*)d_in[26];
  const float* bout    = (const float*)d_in[27];
  const float* Wh0     = (const float*)d_in[28];
  const float* bh0     = (const float*)d_in[29];

  float* ws = (float*)d_ws;
  float* giA  = ws;                                   // 2,764,800
  float* giB  = giA + (size_t)N_*3*HE_;               // 2,764,800
  float* x0   = giB + (size_t)N_*3*HE_;               // 1,843,200
  float* eWhT = x0  + (size_t)N_*2*HE_;               // 1,080,000 (4 x 270,000)
  float* eT0f = eWhT;
  float* eT0b = eT0f + (size_t)3*HE_*HE_;
  float* eT1f = eT0b + (size_t)3*HE_*HE_;
  float* eT1b = eT1f + (size_t)3*HE_*HE_;
  // aliases (stream-ordered reuse):
  float* encF = x0;                                   // after gi1 gemms, x0 dead
  float* encB = x0 + (size_t)N_*HE_;
  float* h0A  = giA;                                  // after L1, gi dead
  float* h1A  = giA + (size_t)N_*HD_;
  // decoder packed weights reuse eWhT (dead after L1):
  // 239,616 + 393,216 + 32,768 = 665,600 <= 1,080,000
  float* Wc0   = eWhT;                                // 39 x 6144
  float* Wc1T  = Wc0 + (size_t)39*6144;               // 256 x 1536
  float* WoutT = Wc1T + (size_t)256*1536;             // 256 x 128
  float* Y = (float*)d_out;

  const dim3 blk(256);

  // ---- encoder weight transposes (into eWhT) ----
  ctranspose_kernel<<<dim3(1055), blk, 0, stream>>>(e0f_Whh, eT0f, 3*HE_, HE_, HE_, 3*HE_, 0, 0);
  ctranspose_kernel<<<dim3(1055), blk, 0, stream>>>(e0b_Whh, eT0b, 3*HE_, HE_, HE_, 3*HE_, 0, 0);
  ctranspose_kernel<<<dim3(1055), blk, 0, stream>>>(e1f_Whh, eT1f, 3*HE_, HE_, HE_, 3*HE_, 0, 0);
  ctranspose_kernel<<<dim3(1055), blk, 0, stream>>>(e1b_Whh, eT1b, 3*HE_, HE_, HE_, 3*HE_, 0, 0);
  // ---- encoder layer 0 ----
  gemm_bias_kernel<0><<<dim3(15,48), blk, 0, stream>>>(wv, nullptr, e0f_Wih, e0f_bih, giA, nullptr, N_, 3*HE_, D_);
  gemm_bias_kernel<0><<<dim3(15,48), blk, 0, stream>>>(wv, nullptr, e0b_Wih, e0b_bih, giB, nullptr, N_, 3*HE_, D_);
  enc_layer_persistent<0><<<dim3(16,2), dim3(640), 0, stream>>>(giA, giB, eT0f, eT0b, e0f_bhh, e0b_bhh, x0, nullptr);
  // ---- encoder layer 1 ----
  gemm_bias_kernel<0><<<dim3(15,48), blk, 0, stream>>>(x0, nullptr, e1f_Wih, e1f_bih, giA, nullptr, N_, 3*HE_, 2*HE_);
  gemm_bias_kernel<0><<<dim3(15,48), blk, 0, stream>>>(x0, nullptr, e1b_Wih, e1b_bih, giB, nullptr, N_, 3*HE_, 2*HE_);
  enc_layer_persistent<1><<<dim3(16,2), dim3(640), 0, stream>>>(giA, giB, eT1f, eT1b, e1f_bhh, e1b_bhh, encF, encB);
  // ---- decoder packed weights (eWhT now dead) ----
  pack_dec0_kernel<<<dim3(936), blk, 0, stream>>>(d0_Whh, d0_Wih, Wc0);
  ctranspose_kernel<<<dim3(768), blk, 0, stream>>>(d1_Wih, Wc1T, 3*HD_, HD_, HD_, 1536, 0, 0);
  ctranspose_kernel<<<dim3(768), blk, 0, stream>>>(d1_Whh, Wc1T, 3*HD_, HD_, HD_, 1536, 0, 768);
  ctranspose_kernel<<<dim3(128), blk, 0, stream>>>(Wout,   WoutT, A_,   HD_, HD_, 128, 0, 0);
  // ---- decoder init: h = tanh((encF+encB)@Wh0^T + bh0) -> h0A, h1A ----
  gemm_bias_kernel<2><<<dim3(8,48), blk, 0, stream>>>(encF, encB, Wh0, bh0, h0A, h1A, N_, 2*HD_, HE_);
  // ---- persistent decoder ----
  dec_persistent<<<dim3(N_/12), dim3(512), 0, stream>>>(
      Wc0, Wc1T, WoutT,
      d0_bih, d0_bhh, d1_bih, d1_bhh, bout,
      emb, h0A, h1A, Y);
}

// Round 9
// 7015.036 us; speedup vs baseline: 1.6217x; 1.6217x over previous
//
#include <hip/hip_runtime.h>
#include <math.h>

#define S_ 48
#define B_ 64
#define D_ 300
#define HE_ 300
#define HD_ 256
#define E_ 50
#define A_ 128
#define T_ 50
#define N_ (S_*B_)   // 3072

__device__ __forceinline__ float sigm(float x){ return 1.0f/(1.0f + expf(-x)); }

// ---------------------------------------------------------------------------
// Generic GEMM: C(M,N) = A(M,K) @ W(N,K)^T + bias(N)
// MODE 0: store C row-major (A2 unused)
// MODE 2: A-tile = A + A2 elementwise; v = tanh(acc+bias);
//         cols [0,256) -> C[m*256+n], [256,512) -> C2
// ---------------------------------------------------------------------------
template<int MODE>
__global__ __launch_bounds__(256)
void gemm_bias_kernel(const float* __restrict__ A, const float* __restrict__ A2,
                      const float* __restrict__ W,
                      const float* __restrict__ bias, float* __restrict__ C,
                      float* __restrict__ C2, int M, int N, int K)
{
  __shared__ float As[16][64];
  __shared__ float Ws[16][64];
  const int tid = threadIdx.x;
  const int bm = blockIdx.y * 64;
  const int bn = blockIdx.x * 64;
  const int tx = tid & 15, ty = tid >> 4;
  const int lr = tid >> 2;
  const int lk = (tid & 3) << 2;
  float acc[4][4] = {{0.f}};
  for (int kb = 0; kb < K; kb += 16) {
    {
      const int row = bm + lr;
      const int k = kb + lk;
      const float* ap = A + (size_t)row * K + k;
      float4 v = make_float4(0.f,0.f,0.f,0.f);
      if (k + 3 < K) v = *reinterpret_cast<const float4*>(ap);
      else {
        if (k   < K) v.x = ap[0];
        if (k+1 < K) v.y = ap[1];
        if (k+2 < K) v.z = ap[2];
        if (k+3 < K) v.w = ap[3];
      }
      if (MODE == 2) {
        const float* ap2 = A2 + (size_t)row * K + k;
        if (k + 3 < K) {
          float4 v2 = *reinterpret_cast<const float4*>(ap2);
          v.x += v2.x; v.y += v2.y; v.z += v2.z; v.w += v2.w;
        } else {
          if (k   < K) v.x += ap2[0];
          if (k+1 < K) v.y += ap2[1];
          if (k+2 < K) v.z += ap2[2];
          if (k+3 < K) v.w += ap2[3];
        }
      }
      As[lk][lr]=v.x; As[lk+1][lr]=v.y; As[lk+2][lr]=v.z; As[lk+3][lr]=v.w;
    }
    {
      const int col = bn + lr;
      const int k = kb + lk;
      float4 v = make_float4(0.f,0.f,0.f,0.f);
      if (col < N) {
        const float* wp = W + (size_t)col * K + k;
        if (k + 3 < K) v = *reinterpret_cast<const float4*>(wp);
        else {
          if (k   < K) v.x = wp[0];
          if (k+1 < K) v.y = wp[1];
          if (k+2 < K) v.z = wp[2];
          if (k+3 < K) v.w = wp[3];
        }
      }
      Ws[lk][lr]=v.x; Ws[lk+1][lr]=v.y; Ws[lk+2][lr]=v.z; Ws[lk+3][lr]=v.w;
    }
    __syncthreads();
    #pragma unroll
    for (int kk = 0; kk < 16; ++kk) {
      float4 a4 = *reinterpret_cast<const float4*>(&As[kk][ty<<2]);
      float4 w4 = *reinterpret_cast<const float4*>(&Ws[kk][tx<<2]);
      const float* a = reinterpret_cast<const float*>(&a4);
      const float* w = reinterpret_cast<const float*>(&w4);
      #pragma unroll
      for (int i = 0; i < 4; ++i)
        #pragma unroll
        for (int j = 0; j < 4; ++j)
          acc[i][j] = fmaf(a[i], w[j], acc[i][j]);
    }
    __syncthreads();
  }
  #pragma unroll
  for (int i = 0; i < 4; ++i) {
    const int m = bm + (ty<<2) + i;
    #pragma unroll
    for (int j = 0; j < 4; ++j) {
      const int n = bn + (tx<<2) + j;
      if (n < N) {
        float v = acc[i][j] + bias[n];
        if (MODE == 0) {
          C[(size_t)m*N + n] = v;
        } else {
          v = tanhf(v);
          if (n < HD_) C[(size_t)m*HD_ + n] = v;
          else         C2[(size_t)m*HD_ + (n-HD_)] = v;
        }
      }
    }
  }
}

// ---------------------------------------------------------------------------
// Padded transpose into strided destination:
// out[(row0+k)*dstride + coff + gc] = in[gc*NK + k]  (zero for k in [NK,NKP))
// ---------------------------------------------------------------------------
__global__ __launch_bounds__(256)
void ctranspose_kernel(const float* __restrict__ in, float* __restrict__ out,
                       int NC, int NK, int NKP, int dstride, int row0, int coff)
{
  int idx = blockIdx.x * 256 + threadIdx.x;
  if (idx < NC*NKP) {
    int gc = idx / NKP, k = idx % NKP;
    out[(size_t)(row0+k)*dstride + coff + gc] =
        (k < NK) ? in[(size_t)gc*NK + k] : 0.0f;
  }
}

// ---------------------------------------------------------------------------
// Pack weights into k-quad float4 layout: P[k4*NC + gc] = W[gc][4*k4 .. +3]
// (zero-padded past NK). W is (NC, NK) row-major. Same values as the scalar
// k-major transpose -> identical FMA sequence in the consumer.
// ---------------------------------------------------------------------------
__global__ __launch_bounds__(256)
void pack4_kernel(const float* __restrict__ W, float4* __restrict__ P,
                  int NC, int NK, int K4)
{
  int idx = blockIdx.x * 256 + threadIdx.x;
  if (idx >= NC * K4) return;
  int k4 = idx / NC, gc = idx % NC;
  int k = k4 << 2;
  const float* wp = W + (size_t)gc * NK + k;
  float4 v = make_float4(0.f,0.f,0.f,0.f);
  if (k   < NK) v.x = wp[0];
  if (k+1 < NK) v.y = wp[1];
  if (k+2 < NK) v.z = wp[2];
  if (k+3 < NK) v.w = wp[3];
  P[(size_t)k4 * NC + gc] = v;
}

// ---------------------------------------------------------------------------
// Persistent encoder layer: grid (16 row-groups, 2 dirs) = 32 blocks, 640 thr.
// (round-6 proven, verbatim)
// ---------------------------------------------------------------------------
template<int LAYER>
__global__ __launch_bounds__(640, 2)
void enc_layer_persistent(const float* __restrict__ gi_f, const float* __restrict__ gi_b,
                          const float* __restrict__ WhhT_f, const float* __restrict__ WhhT_b,
                          const float* __restrict__ bhh_f, const float* __restrict__ bhh_b,
                          float* __restrict__ out, float* __restrict__ outB)
{
  const int dir = blockIdx.y;
  const float* gi  = dir ? gi_b   : gi_f;
  const float* WT  = dir ? WhhT_b : WhhT_f;
  const float* bhh = dir ? bhh_b  : bhh_f;
  float* o = (LAYER == 1 && dir) ? outB : out;

  __shared__ float hA[4][304];
  __shared__ float hB[4][304];
  const int tid = threadIdx.x;
  const int half = tid / 320;
  const int j = tid - half*320;
  const int R0 = blockIdx.x * 4;
  const int r0 = half * 2;
  const bool act = (j < HE_);

  float b_r = 0.f, b_z = 0.f, b_n = 0.f;
  if (act) { b_r = bhh[j]; b_z = bhh[HE_+j]; b_n = bhh[2*HE_+j]; }
  __syncthreads();

  for (int t = 0; t < S_; ++t) {
    const int tt = dir ? (S_-1 - t) : t;
    float (*hin)[304]  = (t & 1) ? hB : hA;
    float (*hout)[304] = (t & 1) ? hA : hB;
    float ar[2]={0,0}, az[2]={0,0}, an[2]={0,0};
    if (act && t > 0) {
      for (int k = 0; k < HE_; k += 4) {
        float wr[4], wz[4], wn[4];
        #pragma unroll
        for (int u = 0; u < 4; ++u) {
          const float* wk = WT + (size_t)(k+u)*(3*HE_);
          wr[u] = wk[j]; wz[u] = wk[HE_+j]; wn[u] = wk[2*HE_+j];
        }
        #pragma unroll
        for (int r = 0; r < 2; ++r) {
          float4 h4 = *reinterpret_cast<const float4*>(&hin[r0+r][k]);
          ar[r]=fmaf(h4.x,wr[0],ar[r]); ar[r]=fmaf(h4.y,wr[1],ar[r]);
          ar[r]=fmaf(h4.z,wr[2],ar[r]); ar[r]=fmaf(h4.w,wr[3],ar[r]);
          az[r]=fmaf(h4.x,wz[0],az[r]); az[r]=fmaf(h4.y,wz[1],az[r]);
          az[r]=fmaf(h4.z,wz[2],az[r]); az[r]=fmaf(h4.w,wz[3],az[r]);
          an[r]=fmaf(h4.x,wn[0],an[r]); an[r]=fmaf(h4.y,wn[1],an[r]);
          an[r]=fmaf(h4.z,wn[2],an[r]); an[r]=fmaf(h4.w,wn[3],an[r]);
        }
      }
    }
    if (act) {
      #pragma unroll
      for (int r = 0; r < 2; ++r) {
        const int row = R0 + r0 + r;
        const size_t gb = (size_t)(tt*B_ + row) * (3*HE_);
        float gr = gi[gb + j];
        float gz = gi[gb + HE_ + j];
        float gn = gi[gb + 2*HE_ + j];
        float rg = sigm(gr + ar[r] + b_r);
        float zg = sigm(gz + az[r] + b_z);
        float ng = tanhf(gn + rg*(an[r] + b_n));
        float ho = (t > 0) ? hin[r0+r][j] : 0.0f;
        float hn = (1.0f - zg)*ng + zg*ho;
        hout[r0+r][j] = hn;
        if (LAYER == 0) o[(size_t)(tt*B_ + row)*(2*HE_) + dir*HE_ + j] = hn;
        else            o[(size_t)(tt*B_ + row)*HE_ + j] = hn;
      }
    }
    __syncthreads();
  }
}

// ---------------------------------------------------------------------------
// Persistent decoder. 256 blocks x 512 threads (1 block/CU, 8 waves).
// Round-5 merged-loop structure (proven, absmax 0.03125) with:
//  - k-quad float4 packed weights (4x fewer VMEM instructions, same FMA order)
//  - __launch_bounds__(512,2): 256-VGPR budget so loads pipeline across kq.
// Weights stream from L2 (FETCH stays ~MB: whole set is L2-resident).
// Thread: c = tid&255 (hidden col), half = tid>>8 -> rows half*6..+5.
// ---------------------------------------------------------------------------
__global__ __launch_bounds__(512, 2)
void dec_persistent(const float4* __restrict__ Wih0P,  // [13][768]
                    const float4* __restrict__ Whh0P,  // [64][768]
                    const float4* __restrict__ Wih1P,  // [64][768]
                    const float4* __restrict__ Whh1P,  // [64][768]
                    const float* __restrict__ WoutT,   // [256][128]
                    const float* __restrict__ bih0, const float* __restrict__ bhh0,
                    const float* __restrict__ bih1, const float* __restrict__ bhh1,
                    const float* __restrict__ bout,
                    const float* __restrict__ emb,
                    const float* __restrict__ h0init, const float* __restrict__ h1init,
                    float* __restrict__ Y)
{
  __shared__ __align__(16) float h0s[12][256];
  __shared__ __align__(16) float h1s[12][256];
  __shared__ __align__(16) float es[12][52];
  const int tid = threadIdx.x;
  const int R0 = blockIdx.x * 12;
  const int c  = tid & 255;
  const int half = tid >> 8;
  const int r0 = half * 6;
  const int lane = tid & 63;
  const int wave = tid >> 6;

  for (int i = tid; i < 12*64; i += 512) {
    int r = i >> 6, k = (i & 63) << 2;
    *reinterpret_cast<float4*>(&h0s[r][k]) =
        *reinterpret_cast<const float4*>(&h0init[(size_t)(R0+r)*HD_ + k]);
    *reinterpret_cast<float4*>(&h1s[r][k]) =
        *reinterpret_cast<const float4*>(&h1init[(size_t)(R0+r)*HD_ + k]);
  }
  for (int i = tid; i < 12*52; i += 512) {
    int r = i / 52, k = i - r*52;
    es[r][k] = (k < E_) ? emb[E_ + k] : 0.0f;   // emb[SOS=1], zero pad
  }
  const float b0r = bih0[c] + bhh0[c];
  const float b0z = bih0[HD_+c] + bhh0[HD_+c];
  const float b0ni = bih0[2*HD_+c];
  const float b0nh = bhh0[2*HD_+c];
  const float b1r = bih1[c] + bhh1[c];
  const float b1z = bih1[HD_+c] + bhh1[HD_+c];
  const float b1ni = bih1[2*HD_+c];
  const float b1nh = bhh1[2*HD_+c];
  const float bo0 = bout[lane];
  const float bo1 = bout[64 + lane];
  __syncthreads();

  for (int s = 0; s < T_-1; ++s) {
    // ===== cell 0 (merged): hh over h0s (K=256) + ih over es (K=52) =======
    float ar[6]={0,0,0,0,0,0}, az[6]={0,0,0,0,0,0};
    float ani[6]={0,0,0,0,0,0}, anh[6]={0,0,0,0,0,0};
    for (int kq = 0; kq < 64; ++kq) {
      const int k = kq << 2;
      float4 wr = Whh0P[kq*768 + c];
      float4 wz = Whh0P[kq*768 + 256 + c];
      float4 wn = Whh0P[kq*768 + 512 + c];
      #pragma unroll
      for (int r = 0; r < 6; ++r) {
        float4 x = *reinterpret_cast<const float4*>(&h0s[r0+r][k]);
        ar[r]=fmaf(x.x,wr.x,ar[r]); ar[r]=fmaf(x.y,wr.y,ar[r]);
        ar[r]=fmaf(x.z,wr.z,ar[r]); ar[r]=fmaf(x.w,wr.w,ar[r]);
        az[r]=fmaf(x.x,wz.x,az[r]); az[r]=fmaf(x.y,wz.y,az[r]);
        az[r]=fmaf(x.z,wz.z,az[r]); az[r]=fmaf(x.w,wz.w,az[r]);
        anh[r]=fmaf(x.x,wn.x,anh[r]); anh[r]=fmaf(x.y,wn.y,anh[r]);
        anh[r]=fmaf(x.z,wn.z,anh[r]); anh[r]=fmaf(x.w,wn.w,anh[r]);
      }
      if (kq < 13) {
        float4 vr = Wih0P[kq*768 + c];
        float4 vz = Wih0P[kq*768 + 256 + c];
        float4 vn = Wih0P[kq*768 + 512 + c];
        #pragma unroll
        for (int r = 0; r < 6; ++r) {
          float4 e = *reinterpret_cast<const float4*>(&es[r0+r][k]);
          ar[r]=fmaf(e.x,vr.x,ar[r]); ar[r]=fmaf(e.y,vr.y,ar[r]);
          ar[r]=fmaf(e.z,vr.z,ar[r]); ar[r]=fmaf(e.w,vr.w,ar[r]);
          az[r]=fmaf(e.x,vz.x,az[r]); az[r]=fmaf(e.y,vz.y,az[r]);
          az[r]=fmaf(e.z,vz.z,az[r]); az[r]=fmaf(e.w,vz.w,az[r]);
          ani[r]=fmaf(e.x,vn.x,ani[r]); ani[r]=fmaf(e.y,vn.y,ani[r]);
          ani[r]=fmaf(e.z,vn.z,ani[r]); ani[r]=fmaf(e.w,vn.w,ani[r]);
        }
      }
    }
    __syncthreads();
    {
      float hnew[6];
      #pragma unroll
      for (int r = 0; r < 6; ++r) {
        float rg = sigm(ar[r] + b0r);
        float zg = sigm(az[r] + b0z);
        float ng = tanhf(ani[r] + b0ni + rg*(anh[r] + b0nh));
        float hold = h0s[r0+r][c];
        hnew[r] = (1.0f - zg)*ng + zg*hold;
      }
      #pragma unroll
      for (int r = 0; r < 6; ++r) h0s[r0+r][c] = hnew[r];
    }
    __syncthreads();
    // ===== cell 1 (merged): ih over h0s + hh over h1s, both K=256 =========
    #pragma unroll
    for (int r = 0; r < 6; ++r) { ar[r]=0.f; az[r]=0.f; ani[r]=0.f; anh[r]=0.f; }
    for (int kq = 0; kq < 64; ++kq) {
      const int k = kq << 2;
      float4 vr = Wih1P[kq*768 + c];
      float4 vz = Wih1P[kq*768 + 256 + c];
      float4 vn = Wih1P[kq*768 + 512 + c];
      float4 wr = Whh1P[kq*768 + c];
      float4 wz = Whh1P[kq*768 + 256 + c];
      float4 wn = Whh1P[kq*768 + 512 + c];
      #pragma unroll
      for (int r = 0; r < 6; ++r) {
        float4 x = *reinterpret_cast<const float4*>(&h0s[r0+r][k]);
        ar[r]=fmaf(x.x,vr.x,ar[r]); ar[r]=fmaf(x.y,vr.y,ar[r]);
        ar[r]=fmaf(x.z,vr.z,ar[r]); ar[r]=fmaf(x.w,vr.w,ar[r]);
        az[r]=fmaf(x.x,vz.x,az[r]); az[r]=fmaf(x.y,vz.y,az[r]);
        az[r]=fmaf(x.z,vz.z,az[r]); az[r]=fmaf(x.w,vz.w,az[r]);
        ani[r]=fmaf(x.x,vn.x,ani[r]); ani[r]=fmaf(x.y,vn.y,ani[r]);
        ani[r]=fmaf(x.z,vn.z,ani[r]); ani[r]=fmaf(x.w,vn.w,ani[r]);
        float4 y = *reinterpret_cast<const float4*>(&h1s[r0+r][k]);
        ar[r]=fmaf(y.x,wr.x,ar[r]); ar[r]=fmaf(y.y,wr.y,ar[r]);
        ar[r]=fmaf(y.z,wr.z,ar[r]); ar[r]=fmaf(y.w,wr.w,ar[r]);
        az[r]=fmaf(y.x,wz.x,az[r]); az[r]=fmaf(y.y,wz.y,az[r]);
        az[r]=fmaf(y.z,wz.z,az[r]); az[r]=fmaf(y.w,wz.w,az[r]);
        anh[r]=fmaf(y.x,wn.x,anh[r]); anh[r]=fmaf(y.y,wn.y,anh[r]);
        anh[r]=fmaf(y.z,wn.z,anh[r]); anh[r]=fmaf(y.w,wn.w,anh[r]);
      }
    }
    __syncthreads();
    {
      float hnew[6];
      #pragma unroll
      for (int r = 0; r < 6; ++r) {
        float rg = sigm(ar[r] + b1r);
        float zg = sigm(az[r] + b1z);
        float ng = tanhf(ani[r] + b1ni + rg*(anh[r] + b1nh));
        float hold = h1s[r0+r][c];
        hnew[r] = (1.0f - zg)*ng + zg*hold;
      }
      #pragma unroll
      for (int r = 0; r < 6; ++r) h1s[r0+r][c] = hnew[r];
    }
    __syncthreads();
    // ===== logits + log_softmax + argmax + emb feedback (8 waves, rr+=8) ===
    for (int rr = wave; rr < 12; rr += 8) {
      float a0 = 0.f, a1 = 0.f;
      for (int k = 0; k < HD_; k += 2) {
        float w00 = WoutT[(size_t)k*A_ + lane];
        float w01 = WoutT[(size_t)k*A_ + 64 + lane];
        float w10 = WoutT[(size_t)(k+1)*A_ + lane];
        float w11 = WoutT[(size_t)(k+1)*A_ + 64 + lane];
        float2 hv = *reinterpret_cast<const float2*>(&h1s[rr][k]);
        a0 = fmaf(hv.x, w00, a0); a0 = fmaf(hv.y, w10, a0);
        a1 = fmaf(hv.x, w01, a1); a1 = fmaf(hv.y, w11, a1);
      }
      float v0 = a0 + bo0;
      float v1 = a1 + bo1;
      float mx = fmaxf(v0, v1);
      #pragma unroll
      for (int off = 32; off >= 1; off >>= 1) mx = fmaxf(mx, __shfl_xor(mx, off));
      float sum = expf(v0 - mx) + expf(v1 - mx);
      #pragma unroll
      for (int off = 32; off >= 1; off >>= 1) sum += __shfl_xor(sum, off);
      float lz = mx + logf(sum);
      float* Yr = Y + ((size_t)s*N_ + R0 + rr)*A_;
      Yr[lane]      = v0 - lz;
      Yr[64 + lane] = v1 - lz;
      float bv; int bi;
      if (v0 >= v1) { bv = v0; bi = lane; } else { bv = v1; bi = 64 + lane; }
      #pragma unroll
      for (int off = 32; off >= 1; off >>= 1) {
        float ov = __shfl_xor(bv, off);
        int   oi = __shfl_xor(bi, off);
        if (ov > bv || (ov == bv && oi < bi)) { bv = ov; bi = oi; }
      }
      if (lane < E_) es[rr][lane] = emb[(size_t)bi*E_ + lane];
    }
    __syncthreads();
  }
}

// ---------------------------------------------------------------------------
extern "C" void kernel_launch(void* const* d_in, const int* in_sizes, int n_in,
                              void* d_out, int out_size, void* d_ws, size_t ws_size,
                              hipStream_t stream)
{
  (void)in_sizes; (void)n_in; (void)out_size; (void)ws_size;
  const float* wv      = (const float*)d_in[0];
  const float* e0f_Wih = (const float*)d_in[1];
  const float* e0f_Whh = (const float*)d_in[2];
  const float* e0f_bih = (const float*)d_in[3];
  const float* e0f_bhh = (const float*)d_in[4];
  const float* e0b_Wih = (const float*)d_in[5];
  const float* e0b_Whh = (const float*)d_in[6];
  const float* e0b_bih = (const float*)d_in[7];
  const float* e0b_bhh = (const float*)d_in[8];
  const float* e1f_Wih = (const float*)d_in[9];
  const float* e1f_Whh = (const float*)d_in[10];
  const float* e1f_bih = (const float*)d_in[11];
  const float* e1f_bhh = (const float*)d_in[12];
  const float* e1b_Wih = (const float*)d_in[13];
  const float* e1b_Whh = (const float*)d_in[14];
  const float* e1b_bih = (const float*)d_in[15];
  const float* e1b_bhh = (const float*)d_in[16];
  const float* d0_Wih  = (const float*)d_in[17];
  const float* d0_Whh  = (const float*)d_in[18];
  const float* d0_bih  = (const float*)d_in[19];
  const float* d0_bhh  = (const float*)d_in[20];
  const float* d1_Wih  = (const float*)d_in[21];
  const float* d1_Whh  = (const float*)d_in[22];
  const float* d1_bih  = (const float*)d_in[23];
  const float* d1_bhh  = (const float*)d_in[24];
  const float* emb     = (const float*)d_in[25];
  const float* Wout    = (const float*)d_in[26];
  const float* bout    = (const float*)d_in[27];
  const float* Wh0     = (const float*)d_in[28];
  const float* bh0     = (const float*)d_in[29];

  float* ws = (float*)d_ws;
  float* giA  = ws;                                   // 2,764,800
  float* giB  = giA + (size_t)N_*3*HE_;               // 2,764,800
  float* x0   = giB + (size_t)N_*3*HE_;               // 1,843,200
  float* eWhT = x0  + (size_t)N_*2*HE_;               // 1,080,000 (4 x 270,000)
  float* eT0f = eWhT;
  float* eT0b = eT0f + (size_t)3*HE_*HE_;
  float* eT1f = eT0b + (size_t)3*HE_*HE_;
  float* eT1b = eT1f + (size_t)3*HE_*HE_;
  // aliases (stream-ordered reuse):
  float* encF = x0;                                   // after gi1 gemms, x0 dead
  float* encB = x0 + (size_t)N_*HE_;
  float* h0A  = giA;                                  // after L1, gi dead
  float* h1A  = giA + (size_t)N_*HD_;
  // packed decoder weights reuse eWhT (dead after enc L1):
  // (13+64+64+64)*768*4 + 256*128 = 662,528 <= 1,080,000
  float4* Wih0P = (float4*)eWhT;                      // 13 x 768
  float4* Whh0P = Wih0P + (size_t)13*768;             // 64 x 768
  float4* Wih1P = Whh0P + (size_t)64*768;
  float4* Whh1P = Wih1P + (size_t)64*768;
  float*  WoutT = (float*)(Whh1P + (size_t)64*768);   // 256 x 128
  float* Y = (float*)d_out;

  const dim3 blk(256);

  // ---- encoder weight transposes (into eWhT) ----
  ctranspose_kernel<<<dim3(1055), blk, 0, stream>>>(e0f_Whh, eT0f, 3*HE_, HE_, HE_, 3*HE_, 0, 0);
  ctranspose_kernel<<<dim3(1055), blk, 0, stream>>>(e0b_Whh, eT0b, 3*HE_, HE_, HE_, 3*HE_, 0, 0);
  ctranspose_kernel<<<dim3(1055), blk, 0, stream>>>(e1f_Whh, eT1f, 3*HE_, HE_, HE_, 3*HE_, 0, 0);
  ctranspose_kernel<<<dim3(1055), blk, 0, stream>>>(e1b_Whh, eT1b, 3*HE_, HE_, HE_, 3*HE_, 0, 0);
  // ---- encoder layer 0 ----
  gemm_bias_kernel<0><<<dim3(15,48), blk, 0, stream>>>(wv, nullptr, e0f_Wih, e0f_bih, giA, nullptr, N_, 3*HE_, D_);
  gemm_bias_kernel<0><<<dim3(15,48), blk, 0, stream>>>(wv, nullptr, e0b_Wih, e0b_bih, giB, nullptr, N_, 3*HE_, D_);
  enc_layer_persistent<0><<<dim3(16,2), dim3(640), 0, stream>>>(giA, giB, eT0f, eT0b, e0f_bhh, e0b_bhh, x0, nullptr);
  // ---- encoder layer 1 ----
  gemm_bias_kernel<0><<<dim3(15,48), blk, 0, stream>>>(x0, nullptr, e1f_Wih, e1f_bih, giA, nullptr, N_, 3*HE_, 2*HE_);
  gemm_bias_kernel<0><<<dim3(15,48), blk, 0, stream>>>(x0, nullptr, e1b_Wih, e1b_bih, giB, nullptr, N_, 3*HE_, 2*HE_);
  enc_layer_persistent<1><<<dim3(16,2), dim3(640), 0, stream>>>(giA, giB, eT1f, eT1b, e1f_bhh, e1b_bhh, encF, encB);
  // ---- packed decoder weights (eWhT now dead) ----
  pack4_kernel<<<dim3(39),  blk, 0, stream>>>(d0_Wih, Wih0P, 3*HD_, E_,  13);
  pack4_kernel<<<dim3(192), blk, 0, stream>>>(d0_Whh, Whh0P, 3*HD_, HD_, 64);
  pack4_kernel<<<dim3(192), blk, 0, stream>>>(d1_Wih, Wih1P, 3*HD_, HD_, 64);
  pack4_kernel<<<dim3(192), blk, 0, stream>>>(d1_Whh, Whh1P, 3*HD_, HD_, 64);
  ctranspose_kernel<<<dim3(128), blk, 0, stream>>>(Wout, WoutT, A_, HD_, HD_, 128, 0, 0);
  // ---- decoder init: h = tanh((encF+encB)@Wh0^T + bh0) -> h0A, h1A ----
  gemm_bias_kernel<2><<<dim3(8,48), blk, 0, stream>>>(encF, encB, Wh0, bh0, h0A, h1A, N_, 2*HD_, HE_);
  // ---- persistent decoder ----
  dec_persistent<<<dim3(N_/12), dim3(512), 0, stream>>>(
      Wih0P, Whh0P, Wih1P, Whh1P, WoutT,
      d0_bih, d0_bhh, d1_bih, d1_bhh, bout,
      emb, h0A, h1A, Y);
}